// Round 1
// baseline (1013.652 us; speedup 1.0000x reference)
//
#include <hip/hip_runtime.h>

#define D 128  // D_IN == D_OUT == 128

// ---------------------------------------------------------------------------
// GEMM: support[n][128] = x[n][128] @ w[128][128]
// W staged in LDS (64 KB). 256 threads/block = 2 rows/block-pass, 1 thread
// per output element. x row elements broadcast across the 128 threads of a
// row (same address -> L1 broadcast).
// ---------------------------------------------------------------------------
__global__ __launch_bounds__(256) void gc_gemm(const float* __restrict__ x,
                                               const float* __restrict__ w,
                                               float* __restrict__ support,
                                               int n_nodes) {
    __shared__ float wlds[D * D];  // 64 KiB
    int tid = threadIdx.x;
    const float4* w4 = (const float4*)w;
    float4* wl4 = (float4*)wlds;
    for (int i = tid; i < D * D / 4; i += 256) wl4[i] = w4[i];
    __syncthreads();

    int col = tid & (D - 1);
    int row_in_blk = tid >> 7;  // 0..1
    for (int row = blockIdx.x * 2 + row_in_blk; row < n_nodes;
         row += gridDim.x * 2) {
        const float* xr = x + (size_t)row * D;
        float acc = 0.f;
#pragma unroll 8
        for (int k = 0; k < D; ++k) acc = fmaf(xr[k], wlds[k * D + col], acc);
        support[(size_t)row * D + col] = acc;
    }
}

// ---------------------------------------------------------------------------
// Init: out[i][j] = bias[j]   (d_out is poisoned 0xAA before every launch)
// ---------------------------------------------------------------------------
__global__ __launch_bounds__(256) void gc_init(float* __restrict__ out,
                                               const float* __restrict__ bias,
                                               int total4) {
    int idx = blockIdx.x * blockDim.x + threadIdx.x;
    if (idx >= total4) return;
    const float4* b4 = (const float4*)bias;
    ((float4*)out)[idx] = b4[idx & (D / 4 - 1)];
}

// ---------------------------------------------------------------------------
// Scatter: one wave (64 lanes) per edge. Each lane handles 2 columns via
// float2. out[dst] += val * support[src]  (device-scope atomicAdd).
// ---------------------------------------------------------------------------
__global__ __launch_bounds__(256) void gc_scatter(const float* __restrict__ support,
                                                  const int* __restrict__ src,
                                                  const int* __restrict__ dst,
                                                  const float* __restrict__ val,
                                                  float* __restrict__ out,
                                                  int n_edges) {
    int gid = blockIdx.x * blockDim.x + threadIdx.x;
    int edge = gid >> 6;
    int lane = threadIdx.x & 63;
    if (edge >= n_edges) return;

    int s = src[edge];            // wave-uniform load (broadcast)
    int d = dst[edge];
    float v = val[edge];

    const float2* sp = (const float2*)(support + (size_t)s * D);
    float2 g = sp[lane];
    float* op = out + (size_t)d * D + lane * 2;
    atomicAdd(op + 0, g.x * v);
    atomicAdd(op + 1, g.y * v);
}

extern "C" void kernel_launch(void* const* d_in, const int* in_sizes, int n_in,
                              void* d_out, int out_size, void* d_ws, size_t ws_size,
                              hipStream_t stream) {
    const float* x        = (const float*)d_in[0];
    const int*   edge_src = (const int*)d_in[1];
    const int*   edge_dst = (const int*)d_in[2];
    const float* edge_val = (const float*)d_in[3];
    const float* weight   = (const float*)d_in[4];
    const float* bias     = (const float*)d_in[5];
    float*       out      = (float*)d_out;

    const int n_nodes = in_sizes[0] / D;   // 50000
    const int n_edges = in_sizes[1];       // 800000

    float* support = (float*)d_ws;         // n_nodes * 128 * 4 = 25.6 MB

    // 1) support = x @ w
    {
        int grid = (n_nodes + 1) / 2;
        gc_gemm<<<grid, 256, 0, stream>>>(x, weight, support, n_nodes);
    }
    // 2) out = bias (broadcast)
    {
        int total4 = n_nodes * D / 4;
        int grid = (total4 + 255) / 256;
        gc_init<<<grid, 256, 0, stream>>>(out, bias, total4);
    }
    // 3) out[dst] += val * support[src]
    {
        long long threads = (long long)n_edges * 64;
        int grid = (int)((threads + 255) / 256);
        gc_scatter<<<grid, 256, 0, stream>>>(support, edge_src, edge_dst,
                                             edge_val, out, n_edges);
    }
}

// Round 2
// 299.390 us; speedup vs baseline: 3.3857x; 3.3857x over previous
//
#include <hip/hip_runtime.h>

#define D 128  // D_IN == D_OUT == 128

// ===========================================================================
// GEMM: support[n][128] = x[n][128] @ w[128][128]
// 32-row tiles. 256 threads: c4 = tid&31 (float4 col group), rt = (tid>>5)*4
// (4 consecutive rows). W (64 KB) + x-tile (16 KB) in LDS. All LDS reads are
// b128; 16 FMAs per 1 w-read + amortized x-read.
// ===========================================================================
__global__ __launch_bounds__(256) void gc_gemm(const float* __restrict__ x,
                                               const float* __restrict__ w,
                                               float* __restrict__ support,
                                               int n_nodes) {
    __shared__ float4 wl4[D * 32];   // 64 KiB  (w[k][c] as float4 cols)
    __shared__ float4 xl4[32 * 32];  // 16 KiB  (x[r][k] as float4 k-groups)

    const int tid = threadIdx.x;
    const float4* w4 = (const float4*)w;
    const float4* x4 = (const float4*)x;

#pragma unroll
    for (int i = tid; i < D * 32; i += 256) wl4[i] = w4[i];

    const int c4 = tid & 31;
    const int rt = (tid >> 5) * 4;
    const int row0 = blockIdx.x * 32;

    // stage x tile (guarded)
    const float4 zero4 = {0.f, 0.f, 0.f, 0.f};
    for (int i = tid; i < 32 * 32; i += 256) {
        int r = i >> 5, k4 = i & 31;
        int row = row0 + r;
        xl4[i] = (row < n_nodes) ? x4[(size_t)row * 32 + k4] : zero4;
    }
    __syncthreads();

    float4 acc[4];
#pragma unroll
    for (int m = 0; m < 4; ++m) acc[m] = zero4;

    for (int k4 = 0; k4 < 32; ++k4) {
        float4 xa[4];
#pragma unroll
        for (int m = 0; m < 4; ++m) xa[m] = xl4[(rt + m) * 32 + k4];
#pragma unroll
        for (int kk = 0; kk < 4; ++kk) {
            float4 wv = wl4[(k4 * 4 + kk) * 32 + c4];
#pragma unroll
            for (int m = 0; m < 4; ++m) {
                float xs = (kk == 0) ? xa[m].x : (kk == 1) ? xa[m].y
                         : (kk == 2) ? xa[m].z : xa[m].w;
                acc[m].x = fmaf(xs, wv.x, acc[m].x);
                acc[m].y = fmaf(xs, wv.y, acc[m].y);
                acc[m].z = fmaf(xs, wv.z, acc[m].z);
                acc[m].w = fmaf(xs, wv.w, acc[m].w);
            }
        }
    }

    float4* s4 = (float4*)support;
#pragma unroll
    for (int m = 0; m < 4; ++m) {
        int row = row0 + rt + m;
        if (row < n_nodes) s4[(size_t)row * 32 + c4] = acc[m];
    }
}

// ===========================================================================
// CSR build: zero -> histogram -> 3-pass exclusive scan -> fill
// ===========================================================================
__global__ __launch_bounds__(256) void gc_zero(int* __restrict__ p, int n) {
    int i = blockIdx.x * 256 + threadIdx.x;
    if (i < n) p[i] = 0;
}

__global__ __launch_bounds__(256) void gc_hist(const int* __restrict__ dst,
                                               int* __restrict__ cnt, int n_edges) {
    int e = blockIdx.x * 256 + threadIdx.x;
    if (e < n_edges) atomicAdd(&cnt[dst[e]], 1);
}

__global__ __launch_bounds__(1024) void gc_scan1(const int* __restrict__ cnt,
                                                 int* __restrict__ bsum, int n) {
    __shared__ int sd[1024];
    int tid = threadIdx.x;
    int i = blockIdx.x * 1024 + tid;
    sd[tid] = (i < n) ? cnt[i] : 0;
    __syncthreads();
#pragma unroll
    for (int off = 512; off > 0; off >>= 1) {
        if (tid < off) sd[tid] += sd[tid + off];
        __syncthreads();
    }
    if (tid == 0) bsum[blockIdx.x] = sd[0];
}

__global__ void gc_scan2(int* __restrict__ bsum, int nb,
                         int* __restrict__ rowptr, int n, int n_edges) {
    if (threadIdx.x == 0 && blockIdx.x == 0) {
        int run = 0;
        for (int b = 0; b < nb; ++b) { int v = bsum[b]; bsum[b] = run; run += v; }
        rowptr[n] = n_edges;
    }
}

__global__ __launch_bounds__(1024) void gc_scan3(const int* __restrict__ cnt,
                                                 const int* __restrict__ bsum,
                                                 int* __restrict__ rowptr,
                                                 int* __restrict__ cursor, int n) {
    __shared__ int sd[1024];
    int tid = threadIdx.x;
    int i = blockIdx.x * 1024 + tid;
    int v = (i < n) ? cnt[i] : 0;
    sd[tid] = v;
    __syncthreads();
    for (int off = 1; off < 1024; off <<= 1) {
        int t = (tid >= off) ? sd[tid - off] : 0;
        __syncthreads();
        sd[tid] += t;
        __syncthreads();
    }
    int excl = sd[tid] - v + bsum[blockIdx.x];
    if (i < n) { rowptr[i] = excl; cursor[i] = excl; }
}

__global__ __launch_bounds__(256) void gc_fill(const int* __restrict__ src,
                                               const int* __restrict__ dst,
                                               const float* __restrict__ val,
                                               int* __restrict__ cursor,
                                               int* __restrict__ csr_src,
                                               float* __restrict__ csr_val,
                                               int n_edges) {
    int e = blockIdx.x * 256 + threadIdx.x;
    if (e >= n_edges) return;
    int p = atomicAdd(&cursor[dst[e]], 1);
    csr_src[p] = src[e];
    csr_val[p] = val[e];
}

// ===========================================================================
// Gather: one wave per dst node; lane holds 2 cols (float2). bias fused.
// ===========================================================================
__global__ __launch_bounds__(256) void gc_gather(const float* __restrict__ support,
                                                 const int* __restrict__ rowptr,
                                                 const int* __restrict__ csr_src,
                                                 const float* __restrict__ csr_val,
                                                 const float* __restrict__ bias,
                                                 float* __restrict__ out, int n) {
    int node = blockIdx.x * 4 + (threadIdx.x >> 6);
    int lane = threadIdx.x & 63;
    if (node >= n) return;

    const float2* sup2 = (const float2*)support;
    float2 acc = ((const float2*)bias)[lane];
    int beg = rowptr[node], end = rowptr[node + 1];
    for (int j = beg; j < end; ++j) {
        int s = csr_src[j];          // wave-uniform -> broadcast
        float v = csr_val[j];
        float2 g = sup2[(size_t)s * 64 + lane];
        acc.x = fmaf(v, g.x, acc.x);
        acc.y = fmaf(v, g.y, acc.y);
    }
    ((float2*)out)[(size_t)node * 64 + lane] = acc;
}

// ---------------------------------------------------------------------------
// Fallback (tiny ws): bias-init + atomic scatter (round-1 path)
// ---------------------------------------------------------------------------
__global__ __launch_bounds__(256) void gc_init(float* __restrict__ out,
                                               const float* __restrict__ bias,
                                               int total4) {
    int idx = blockIdx.x * blockDim.x + threadIdx.x;
    if (idx >= total4) return;
    const float4* b4 = (const float4*)bias;
    ((float4*)out)[idx] = b4[idx & (D / 4 - 1)];
}

__global__ __launch_bounds__(256) void gc_scatter(const float* __restrict__ support,
                                                  const int* __restrict__ src,
                                                  const int* __restrict__ dst,
                                                  const float* __restrict__ val,
                                                  float* __restrict__ out,
                                                  int n_edges) {
    int gid = blockIdx.x * blockDim.x + threadIdx.x;
    int edge = gid >> 6;
    int lane = threadIdx.x & 63;
    if (edge >= n_edges) return;
    int s = src[edge];
    int d = dst[edge];
    float v = val[edge];
    const float2* sp = (const float2*)(support + (size_t)s * D);
    float2 g = sp[lane];
    float* op = out + (size_t)d * D + lane * 2;
    atomicAdd(op + 0, g.x * v);
    atomicAdd(op + 1, g.y * v);
}

extern "C" void kernel_launch(void* const* d_in, const int* in_sizes, int n_in,
                              void* d_out, int out_size, void* d_ws, size_t ws_size,
                              hipStream_t stream) {
    const float* x        = (const float*)d_in[0];
    const int*   edge_src = (const int*)d_in[1];
    const int*   edge_dst = (const int*)d_in[2];
    const float* edge_val = (const float*)d_in[3];
    const float* weight   = (const float*)d_in[4];
    const float* bias     = (const float*)d_in[5];
    float*       out      = (float*)d_out;

    const int n_nodes = in_sizes[0] / D;   // 50000
    const int n_edges = in_sizes[1];       // 800000

    // --- workspace layout (256-B aligned) ---
    size_t off = 0;
    auto take = [&](size_t bytes) {
        size_t p = off;
        off = (off + bytes + 255) & ~(size_t)255;
        return p;
    };
    char* ws = (char*)d_ws;
    size_t o_support = take((size_t)n_nodes * D * 4);
    size_t o_cnt     = take((size_t)n_nodes * 4);
    size_t o_rowptr  = take(((size_t)n_nodes + 1) * 4);
    size_t o_cursor  = take((size_t)n_nodes * 4);
    size_t o_bsum    = take(256 * 4);
    size_t o_csrsrc  = take((size_t)n_edges * 4);
    size_t o_csrval  = take((size_t)n_edges * 4);
    bool csr_ok = (off <= ws_size);

    float* support = (float*)(ws + o_support);

    // 1) support = x @ w
    {
        int grid = (n_nodes + 31) / 32;
        gc_gemm<<<grid, 256, 0, stream>>>(x, weight, support, n_nodes);
    }

    if (csr_ok) {
        int* cnt     = (int*)(ws + o_cnt);
        int* rowptr  = (int*)(ws + o_rowptr);
        int* cursor  = (int*)(ws + o_cursor);
        int* bsum    = (int*)(ws + o_bsum);
        int* csr_src = (int*)(ws + o_csrsrc);
        float* csr_val = (float*)(ws + o_csrval);

        int nb = (n_nodes + 1023) / 1024;

        gc_zero<<<(n_nodes + 255) / 256, 256, 0, stream>>>(cnt, n_nodes);
        gc_hist<<<(n_edges + 255) / 256, 256, 0, stream>>>(edge_dst, cnt, n_edges);
        gc_scan1<<<nb, 1024, 0, stream>>>(cnt, bsum, n_nodes);
        gc_scan2<<<1, 64, 0, stream>>>(bsum, nb, rowptr, n_nodes, n_edges);
        gc_scan3<<<nb, 1024, 0, stream>>>(cnt, bsum, rowptr, cursor, n_nodes);
        gc_fill<<<(n_edges + 255) / 256, 256, 0, stream>>>(
            edge_src, edge_dst, edge_val, cursor, csr_src, csr_val, n_edges);
        gc_gather<<<(n_nodes + 3) / 4, 256, 0, stream>>>(
            support, rowptr, csr_src, csr_val, bias, out, n_nodes);
    } else {
        // fallback: atomic scatter
        int total4 = n_nodes * D / 4;
        gc_init<<<(total4 + 255) / 256, 256, 0, stream>>>(out, bias, total4);
        long long threads = (long long)n_edges * 64;
        int grid = (int)((threads + 255) / 256);
        gc_scatter<<<grid, 256, 0, stream>>>(support, edge_src, edge_dst,
                                             edge_val, out, n_edges);
    }
}